// Round 1
// baseline (116590.576 us; speedup 1.0000x reference)
//
#include <hip/hip_runtime.h>
#include <hip/hip_cooperative_groups.h>
#include <cmath>

namespace cg = cooperative_groups;

#define BB   64      // batch
#define DD   512     // data dim
#define UU   768     // units
#define GG   2304    // 3*UU
#define TIN  64
#define TOUT 64

struct P {
  const float* inputs;
  const float* Wx[3];
  const float* Wh[3];
  const float* bi[3];
  const float* br[3];
  const float* h0[3];
  const float* Wd;
  const float* bd;
  const float* mean;
  const float* stdv;
  float* out;
  float* ws;
};

__device__ __forceinline__ float sigm(float a) { return 1.0f / (1.0f + expf(-a)); }

// Per-cell GRU: block owns gate-columns c = blk*3 .. blk*3+2, all 64 batch rows.
// threads: b = tid>>3 (0..63), kq = tid&7 (k-eighth).
__device__ __forceinline__ void gru_cell(
    const float* __restrict__ x, int xstride, int Kx,
    const float* __restrict__ Wx, const float* __restrict__ Wh,
    const float* __restrict__ bi, const float* __restrict__ br,
    const float* __restrict__ hp, float* __restrict__ hn,
    int blk, int b, int kq)
{
  const float* xrow = x + (size_t)b * xstride;
  const float* hrow = hp + (size_t)b * UU;
  const int kxc = Kx >> 3;   // per-thread x-chunk (64 or 96)
  const int khc = UU >> 3;   // 96

  for (int cc = 0; cc < 3; ++cc) {
    const int c = blk * 3 + cc;
    float axz = 0.f, axr = 0.f, axh = 0.f;
    float ahz = 0.f, ahr = 0.f, ahh = 0.f;
    {
      const float* w  = Wx + c + (size_t)(kq * kxc) * GG;
      const float* xv = xrow + kq * kxc;
      #pragma unroll 4
      for (int k = 0; k < kxc; ++k) {
        float v = xv[k];
        axz = fmaf(v, w[0],      axz);
        axr = fmaf(v, w[UU],     axr);
        axh = fmaf(v, w[2 * UU], axh);
        w += GG;
      }
    }
    {
      const float* w  = Wh + c + (size_t)(kq * khc) * GG;
      const float* hv = hrow + kq * khc;
      #pragma unroll 4
      for (int k = 0; k < khc; ++k) {
        float v = hv[k];
        ahz = fmaf(v, w[0],      ahz);
        ahr = fmaf(v, w[UU],     ahr);
        ahh = fmaf(v, w[2 * UU], ahh);
        w += GG;
      }
    }
    // reduce the 8 k-slices (lanes tid&7 within groups of 8)
    axz += __shfl_xor(axz, 1, 8); axz += __shfl_xor(axz, 2, 8); axz += __shfl_xor(axz, 4, 8);
    axr += __shfl_xor(axr, 1, 8); axr += __shfl_xor(axr, 2, 8); axr += __shfl_xor(axr, 4, 8);
    axh += __shfl_xor(axh, 1, 8); axh += __shfl_xor(axh, 2, 8); axh += __shfl_xor(axh, 4, 8);
    ahz += __shfl_xor(ahz, 1, 8); ahz += __shfl_xor(ahz, 2, 8); ahz += __shfl_xor(ahz, 4, 8);
    ahr += __shfl_xor(ahr, 1, 8); ahr += __shfl_xor(ahr, 2, 8); ahr += __shfl_xor(ahr, 4, 8);
    ahh += __shfl_xor(ahh, 1, 8); ahh += __shfl_xor(ahh, 2, 8); ahh += __shfl_xor(ahh, 4, 8);

    float z  = sigm(axz + bi[c]          + ahz + br[c]);
    float r  = sigm(axr + bi[c + UU]     + ahr + br[c + UU]);
    float hc = tanhf(axh + bi[c + 2*UU]  + r * (ahh + br[c + 2*UU]));
    float hnv = z * hrow[c] + (1.f - z) * hc;
    if (kq == 0) hn[(size_t)b * UU + c] = hnv;
  }
}

// Dense readout + output store + normalization for next AR input.
// 512 threads: output o = blk*128 + (tid>>2), k-quarter kq4 = tid&3.
__device__ __forceinline__ void dense_fn(
    const float* __restrict__ h2, const float* __restrict__ Wd,
    const float* __restrict__ bd, const float* __restrict__ mean,
    const float* __restrict__ stdv, float* __restrict__ out,
    float* __restrict__ xbuf, int s, int blk, int tid)
{
  const int o  = blk * 128 + (tid >> 2);
  const int bb = o >> 9;          // /512
  const int dc = o & 511;
  const int kq = tid & 3;
  const float* hrow = h2 + (size_t)bb * UU;
  const float* hv = hrow + kq * 192;
  const float* w  = Wd + dc + (size_t)(kq * 192) * DD;
  float acc = 0.f;
  #pragma unroll 4
  for (int k = 0; k < 192; ++k) { acc = fmaf(hv[k], w[0], acc); w += DD; }
  acc += __shfl_xor(acc, 1, 4);
  acc += __shfl_xor(acc, 2, 4);
  if (kq == 0) {
    float val = acc + bd[dc];
    out[((size_t)bb * TOUT + s) * DD + dc] = val;
    xbuf[(size_t)bb * DD + dc] = (val - mean[dc]) / stdv[dc];
  }
}

__global__ __launch_bounds__(512, 2) void gru_ar_kernel(P p) {
  cg::grid_group grid = cg::this_grid();
  const int tid = threadIdx.x;
  const int blk = blockIdx.x;
  const int b   = tid >> 3;
  const int kq  = tid & 7;

  float* hbuf = p.ws;                       // [2][3][BB][UU] ping-pong
  float* xbuf = p.ws + 2 * 3 * BB * UU;     // [BB][DD] normalized AR input

  // init parity-0 h states: h[j][b][:] = h0_j
  {
    const int n = 3 * BB * UU;
    const int gsz = gridDim.x * blockDim.x;
    for (int i = blk * blockDim.x + tid; i < n; i += gsz) {
      int j = i / (BB * UU);
      int u = i % UU;
      hbuf[i] = p.h0[j][u];
    }
  }
  grid.sync();

  for (int t = 0; t < TIN + TOUT - 1; ++t) {
    const int pr = t & 1;       // read parity
    const int pw = pr ^ 1;      // write parity
    #pragma unroll 1
    for (int j = 0; j < 3; ++j) {
      const float* x; int xstride, Kx;
      if (j == 0) {
        if (t < TIN) { x = p.inputs + (size_t)t * DD; xstride = TIN * DD; }
        else         { x = xbuf;                       xstride = DD; }
        Kx = DD;
      } else {
        x = hbuf + ((size_t)pw * 3 + (j - 1)) * BB * UU; xstride = UU; Kx = UU;
      }
      const float* hp = hbuf + ((size_t)pr * 3 + j) * BB * UU;
      float*       hn = hbuf + ((size_t)pw * 3 + j) * BB * UU;
      const float* Wxj = (j == 0) ? p.Wx[0] : ((j == 1) ? p.Wx[1] : p.Wx[2]);
      const float* Whj = (j == 0) ? p.Wh[0] : ((j == 1) ? p.Wh[1] : p.Wh[2]);
      const float* bij = (j == 0) ? p.bi[0] : ((j == 1) ? p.bi[1] : p.bi[2]);
      const float* brj = (j == 0) ? p.br[0] : ((j == 1) ? p.br[1] : p.br[2]);
      gru_cell(x, xstride, Kx, Wxj, Whj, bij, brj, hp, hn, blk, b, kq);
      grid.sync();
    }
    if (t >= TIN - 1) {
      const int s = t - (TIN - 1);
      const float* h2 = hbuf + ((size_t)pw * 3 + 2) * BB * UU;
      dense_fn(h2, p.Wd, p.bd, p.mean, p.stdv, p.out, xbuf, s, blk, tid);
      grid.sync();
    }
  }
}

extern "C" void kernel_launch(void* const* d_in, const int* in_sizes, int n_in,
                              void* d_out, int out_size, void* d_ws, size_t ws_size,
                              hipStream_t stream) {
  P p;
  p.inputs = (const float*)d_in[0];
  int k = 1;
  for (int j = 0; j < 3; ++j) {
    p.Wx[j] = (const float*)d_in[k++];
    p.Wh[j] = (const float*)d_in[k++];
    p.bi[j] = (const float*)d_in[k++];
    p.br[j] = (const float*)d_in[k++];
    p.h0[j] = (const float*)d_in[k++];
  }
  p.Wd   = (const float*)d_in[k++];
  p.bd   = (const float*)d_in[k++];
  p.mean = (const float*)d_in[k++];
  p.stdv = (const float*)d_in[k++];
  p.out  = (float*)d_out;
  p.ws   = (float*)d_ws;

  void* args[] = { &p };
  hipLaunchCooperativeKernel((void*)gru_ar_kernel, dim3(256), dim3(512), args, 0, stream);
}

// Round 2
// 59070.056 us; speedup vs baseline: 1.9738x; 1.9738x over previous
//
#include <hip/hip_runtime.h>
#include <hip/hip_cooperative_groups.h>
#include <cmath>

namespace cg = cooperative_groups;

#define BB   64      // batch
#define DD   512     // data dim
#define UU   768     // units
#define GG   2304    // 3*UU
#define TIN  64
#define TOUT 64

struct P {
  const float* inputs;
  const float* Wx[3];
  const float* Wh[3];
  const float* bi[3];
  const float* br[3];
  const float* h0[3];
  const float* Wd;
  const float* bd;
  const float* mean;
  const float* stdv;
  // transposed weights (in ws), [col][k] layout
  const float* WxT[3];
  const float* WhT[3];
  const float* WdT;
  float* out;
  float* ws;   // hbuf/xbuf live at start of ws
};

__device__ __forceinline__ float sigm(float a) { return 1.0f / (1.0f + expf(-a)); }

__device__ __forceinline__ float dot4(float4 a, float4 b, float acc) {
  acc = fmaf(a.x, b.x, acc);
  acc = fmaf(a.y, b.y, acc);
  acc = fmaf(a.z, b.z, acc);
  acc = fmaf(a.w, b.w, acc);
  return acc;
}

// ---------------- tiled transpose: dst[c][r] = src[r][c] ----------------
__global__ __launch_bounds__(256) void transpose_kernel(
    const float* __restrict__ src, float* __restrict__ dst, int R, int C) {
  __shared__ float tile[32][33];
  const int bx = blockIdx.x * 32;  // col base
  const int by = blockIdx.y * 32;  // row base
  const int tx = threadIdx.x;      // 0..31
  const int ty = threadIdx.y;      // 0..7
  #pragma unroll
  for (int i = 0; i < 32; i += 8) {
    tile[ty + i][tx] = src[(size_t)(by + ty + i) * C + (bx + tx)];
  }
  __syncthreads();
  #pragma unroll
  for (int i = 0; i < 32; i += 8) {
    dst[(size_t)(bx + ty + i) * R + (by + tx)] = tile[tx][ty + i];
  }
}

// ---------------- GRU cell, transposed weights ----------------
// block owns gate-columns c = blk*3 .. blk*3+2, all 64 batch rows.
// threads: b = tid>>3 (0..63), kq = tid&7 (k-eighth).
__device__ __forceinline__ void gru_cell_t(
    const float* __restrict__ x, int xstride, int Kx,
    const float* __restrict__ WxT, const float* __restrict__ WhT,
    const float* __restrict__ bi, const float* __restrict__ br,
    const float* __restrict__ hp, float* __restrict__ hn,
    int blk, int b, int kq)
{
  const float* xrow = x + (size_t)b * xstride;
  const float* hrow = hp + (size_t)b * UU;
  const int nx4 = Kx >> 5;   // float4s per thread for x (16 or 24)
  const int nh4 = UU >> 5;   // 24
  const float4* xv = (const float4*)xrow + kq * nx4;
  const float4* hv = (const float4*)hrow + kq * nh4;

  #pragma unroll 1
  for (int cc = 0; cc < 3; ++cc) {
    const int c = blk * 3 + cc;
    float axz = 0.f, axr = 0.f, axh = 0.f;
    float ahz = 0.f, ahr = 0.f, ahh = 0.f;
    {
      const float4* wz = (const float4*)(WxT + (size_t)c          * Kx) + kq * nx4;
      const float4* wr = (const float4*)(WxT + (size_t)(c +   UU) * Kx) + kq * nx4;
      const float4* wh = (const float4*)(WxT + (size_t)(c + 2*UU) * Kx) + kq * nx4;
      #pragma unroll 4
      for (int i = 0; i < nx4; ++i) {
        float4 v = xv[i];
        axz = dot4(v, wz[i], axz);
        axr = dot4(v, wr[i], axr);
        axh = dot4(v, wh[i], axh);
      }
    }
    {
      const float4* wz = (const float4*)(WhT + (size_t)c          * UU) + kq * nh4;
      const float4* wr = (const float4*)(WhT + (size_t)(c +   UU) * UU) + kq * nh4;
      const float4* wh = (const float4*)(WhT + (size_t)(c + 2*UU) * UU) + kq * nh4;
      #pragma unroll 4
      for (int i = 0; i < nh4; ++i) {
        float4 v = hv[i];
        ahz = dot4(v, wz[i], ahz);
        ahr = dot4(v, wr[i], ahr);
        ahh = dot4(v, wh[i], ahh);
      }
    }
    // reduce the 8 k-slices
    axz += __shfl_xor(axz, 1, 8); axz += __shfl_xor(axz, 2, 8); axz += __shfl_xor(axz, 4, 8);
    axr += __shfl_xor(axr, 1, 8); axr += __shfl_xor(axr, 2, 8); axr += __shfl_xor(axr, 4, 8);
    axh += __shfl_xor(axh, 1, 8); axh += __shfl_xor(axh, 2, 8); axh += __shfl_xor(axh, 4, 8);
    ahz += __shfl_xor(ahz, 1, 8); ahz += __shfl_xor(ahz, 2, 8); ahz += __shfl_xor(ahz, 4, 8);
    ahh += __shfl_xor(ahh, 1, 8); ahh += __shfl_xor(ahh, 2, 8); ahh += __shfl_xor(ahh, 4, 8);
    ahr += __shfl_xor(ahr, 1, 8); ahr += __shfl_xor(ahr, 2, 8); ahr += __shfl_xor(ahr, 4, 8);

    float z  = sigm(axz + bi[c]          + ahz + br[c]);
    float r  = sigm(axr + bi[c + UU]     + ahr + br[c + UU]);
    float hc = tanhf(axh + bi[c + 2*UU]  + r * (ahh + br[c + 2*UU]));
    float hnv = z * hrow[c] + (1.f - z) * hc;
    if (kq == 0) hn[(size_t)b * UU + c] = hnv;
  }
}

// ---------------- dense readout, transposed Wd ----------------
__device__ __forceinline__ void dense_t(
    const float* __restrict__ h2, const float* __restrict__ WdT,
    const float* __restrict__ bd, const float* __restrict__ mean,
    const float* __restrict__ stdv, float* __restrict__ out,
    float* __restrict__ xbuf, int s, int blk, int tid)
{
  const int o  = blk * 128 + (tid >> 2);
  const int bb = o >> 9;
  const int dc = o & 511;
  const int kq = tid & 3;
  const float4* hv = (const float4*)(h2 + (size_t)bb * UU) + kq * 48;
  const float4* w  = (const float4*)(WdT + (size_t)dc * UU) + kq * 48;
  float acc = 0.f;
  #pragma unroll 4
  for (int i = 0; i < 48; ++i) acc = dot4(hv[i], w[i], acc);
  acc += __shfl_xor(acc, 1, 4);
  acc += __shfl_xor(acc, 2, 4);
  if (kq == 0) {
    float val = acc + bd[dc];
    out[((size_t)bb * TOUT + s) * DD + dc] = val;
    xbuf[(size_t)bb * DD + dc] = (val - mean[dc]) / stdv[dc];
  }
}

__global__ __launch_bounds__(512, 2) void gru_ar_kernel(P p) {
  cg::grid_group grid = cg::this_grid();
  const int tid = threadIdx.x;
  const int blk = blockIdx.x;
  const int b   = tid >> 3;
  const int kq  = tid & 7;

  float* hbuf = p.ws;                       // [2][3][BB][UU] ping-pong
  float* xbuf = p.ws + 2 * 3 * BB * UU;     // [BB][DD]

  {
    const int n = 3 * BB * UU;
    const int gsz = gridDim.x * blockDim.x;
    for (int i = blk * blockDim.x + tid; i < n; i += gsz) {
      int j = i / (BB * UU);
      int u = i % UU;
      hbuf[i] = p.h0[j][u];
    }
  }
  grid.sync();

  for (int t = 0; t < TIN + TOUT - 1; ++t) {
    const int pr = t & 1;
    const int pw = pr ^ 1;
    #pragma unroll 1
    for (int j = 0; j < 3; ++j) {
      const float* x; int xstride, Kx;
      if (j == 0) {
        if (t < TIN) { x = p.inputs + (size_t)t * DD; xstride = TIN * DD; }
        else         { x = xbuf;                       xstride = DD; }
        Kx = DD;
      } else {
        x = hbuf + ((size_t)pw * 3 + (j - 1)) * BB * UU; xstride = UU; Kx = UU;
      }
      const float* hp = hbuf + ((size_t)pr * 3 + j) * BB * UU;
      float*       hn = hbuf + ((size_t)pw * 3 + j) * BB * UU;
      gru_cell_t(x, xstride, Kx, p.WxT[j], p.WhT[j], p.bi[j], p.br[j],
                 hp, hn, blk, b, kq);
      grid.sync();
    }
    if (t >= TIN - 1) {
      const int s = t - (TIN - 1);
      const float* h2 = hbuf + ((size_t)pw * 3 + 2) * BB * UU;
      dense_t(h2, p.WdT, p.bd, p.mean, p.stdv, p.out, xbuf, s, blk, tid);
      grid.sync();
    }
  }
}

// ---------------- fallback (R1 kernel, untransposed) ----------------
__device__ __forceinline__ void gru_cell_naive(
    const float* __restrict__ x, int xstride, int Kx,
    const float* __restrict__ Wx, const float* __restrict__ Wh,
    const float* __restrict__ bi, const float* __restrict__ br,
    const float* __restrict__ hp, float* __restrict__ hn,
    int blk, int b, int kq)
{
  const float* xrow = x + (size_t)b * xstride;
  const float* hrow = hp + (size_t)b * UU;
  const int kxc = Kx >> 3;
  const int khc = UU >> 3;
  for (int cc = 0; cc < 3; ++cc) {
    const int c = blk * 3 + cc;
    float axz = 0.f, axr = 0.f, axh = 0.f, ahz = 0.f, ahr = 0.f, ahh = 0.f;
    {
      const float* w  = Wx + c + (size_t)(kq * kxc) * GG;
      const float* xv = xrow + kq * kxc;
      for (int k = 0; k < kxc; ++k) {
        float v = xv[k];
        axz = fmaf(v, w[0], axz); axr = fmaf(v, w[UU], axr); axh = fmaf(v, w[2*UU], axh);
        w += GG;
      }
    }
    {
      const float* w  = Wh + c + (size_t)(kq * khc) * GG;
      const float* hv = hrow + kq * khc;
      for (int k = 0; k < khc; ++k) {
        float v = hv[k];
        ahz = fmaf(v, w[0], ahz); ahr = fmaf(v, w[UU], ahr); ahh = fmaf(v, w[2*UU], ahh);
        w += GG;
      }
    }
    axz += __shfl_xor(axz,1,8); axz += __shfl_xor(axz,2,8); axz += __shfl_xor(axz,4,8);
    axr += __shfl_xor(axr,1,8); axr += __shfl_xor(axr,2,8); axr += __shfl_xor(axr,4,8);
    axh += __shfl_xor(axh,1,8); axh += __shfl_xor(axh,2,8); axh += __shfl_xor(axh,4,8);
    ahz += __shfl_xor(ahz,1,8); ahz += __shfl_xor(ahz,2,8); ahz += __shfl_xor(ahz,4,8);
    ahr += __shfl_xor(ahr,1,8); ahr += __shfl_xor(ahr,2,8); ahr += __shfl_xor(ahr,4,8);
    ahh += __shfl_xor(ahh,1,8); ahh += __shfl_xor(ahh,2,8); ahh += __shfl_xor(ahh,4,8);
    float z  = sigm(axz + bi[c]         + ahz + br[c]);
    float r  = sigm(axr + bi[c + UU]    + ahr + br[c + UU]);
    float hc = tanhf(axh + bi[c + 2*UU] + r * (ahh + br[c + 2*UU]));
    float hnv = z * hrow[c] + (1.f - z) * hc;
    if (kq == 0) hn[(size_t)b * UU + c] = hnv;
  }
}

__global__ __launch_bounds__(512, 2) void gru_ar_kernel_naive(P p) {
  cg::grid_group grid = cg::this_grid();
  const int tid = threadIdx.x;
  const int blk = blockIdx.x;
  const int b   = tid >> 3;
  const int kq  = tid & 7;
  float* hbuf = p.ws;
  float* xbuf = p.ws + 2 * 3 * BB * UU;
  {
    const int n = 3 * BB * UU;
    const int gsz = gridDim.x * blockDim.x;
    for (int i = blk * blockDim.x + tid; i < n; i += gsz) {
      int j = i / (BB * UU);
      int u = i % UU;
      hbuf[i] = p.h0[j][u];
    }
  }
  grid.sync();
  for (int t = 0; t < TIN + TOUT - 1; ++t) {
    const int pr = t & 1;
    const int pw = pr ^ 1;
    for (int j = 0; j < 3; ++j) {
      const float* x; int xstride, Kx;
      if (j == 0) {
        if (t < TIN) { x = p.inputs + (size_t)t * DD; xstride = TIN * DD; }
        else         { x = xbuf;                       xstride = DD; }
        Kx = DD;
      } else {
        x = hbuf + ((size_t)pw * 3 + (j - 1)) * BB * UU; xstride = UU; Kx = UU;
      }
      const float* hp = hbuf + ((size_t)pr * 3 + j) * BB * UU;
      float*       hn = hbuf + ((size_t)pw * 3 + j) * BB * UU;
      gru_cell_naive(x, xstride, Kx, p.Wx[j], p.Wh[j], p.bi[j], p.br[j],
                     hp, hn, blk, b, kq);
      grid.sync();
    }
    if (t >= TIN - 1) {
      const int s = t - (TIN - 1);
      const float* h2 = hbuf + ((size_t)pw * 3 + 2) * BB * UU;
      // naive dense: strided Wd access
      const int o  = blk * 128 + (tid >> 2);
      const int bb = o >> 9;
      const int dc = o & 511;
      const int kq4 = tid & 3;
      const float* hv = h2 + (size_t)bb * UU + kq4 * 192;
      const float* w  = p.Wd + dc + (size_t)(kq4 * 192) * DD;
      float acc = 0.f;
      for (int k = 0; k < 192; ++k) { acc = fmaf(hv[k], w[0], acc); w += DD; }
      acc += __shfl_xor(acc, 1, 4);
      acc += __shfl_xor(acc, 2, 4);
      if (kq4 == 0) {
        float val = acc + p.bd[dc];
        p.out[((size_t)bb * TOUT + s) * DD + dc] = val;
        xbuf[(size_t)bb * DD + dc] = (val - p.mean[dc]) / p.stdv[dc];
      }
      grid.sync();
    }
  }
}

extern "C" void kernel_launch(void* const* d_in, const int* in_sizes, int n_in,
                              void* d_out, int out_size, void* d_ws, size_t ws_size,
                              hipStream_t stream) {
  P p;
  p.inputs = (const float*)d_in[0];
  int k = 1;
  for (int j = 0; j < 3; ++j) {
    p.Wx[j] = (const float*)d_in[k++];
    p.Wh[j] = (const float*)d_in[k++];
    p.bi[j] = (const float*)d_in[k++];
    p.br[j] = (const float*)d_in[k++];
    p.h0[j] = (const float*)d_in[k++];
  }
  p.Wd   = (const float*)d_in[k++];
  p.bd   = (const float*)d_in[k++];
  p.mean = (const float*)d_in[k++];
  p.stdv = (const float*)d_in[k++];
  p.out  = (float*)d_out;
  p.ws   = (float*)d_ws;

  // ws layout: hbuf (2*3*BB*UU) | xbuf (BB*DD) | transposed weights
  size_t off = 2 * 3 * BB * UU + BB * DD;
  float* wsf = (float*)d_ws;
  const int KxDims[3] = { DD, UU, UU };
  float* WxT[3]; float* WhT[3]; float* WdT;
  for (int j = 0; j < 3; ++j) {
    WxT[j] = wsf + off; off += (size_t)GG * KxDims[j];
    WhT[j] = wsf + off; off += (size_t)GG * UU;
  }
  WdT = wsf + off; off += (size_t)DD * UU;
  const size_t need_bytes = off * sizeof(float);

  if (ws_size >= need_bytes) {
    dim3 tb(32, 8);
    for (int j = 0; j < 3; ++j) {
      transpose_kernel<<<dim3(GG / 32, KxDims[j] / 32), tb, 0, stream>>>(
          p.Wx[j], WxT[j], KxDims[j], GG);
      transpose_kernel<<<dim3(GG / 32, UU / 32), tb, 0, stream>>>(
          p.Wh[j], WhT[j], UU, GG);
    }
    transpose_kernel<<<dim3(DD / 32, UU / 32), tb, 0, stream>>>(p.Wd, WdT, UU, DD);
    for (int j = 0; j < 3; ++j) { p.WxT[j] = WxT[j]; p.WhT[j] = WhT[j]; }
    p.WdT = WdT;
    void* args[] = { &p };
    hipLaunchCooperativeKernel((void*)gru_ar_kernel, dim3(256), dim3(512), args, 0, stream);
  } else {
    for (int j = 0; j < 3; ++j) { p.WxT[j] = nullptr; p.WhT[j] = nullptr; }
    p.WdT = nullptr;
    void* args[] = { &p };
    hipLaunchCooperativeKernel((void*)gru_ar_kernel_naive, dim3(256), dim3(512), args, 0, stream);
  }
}

// Round 3
// 22017.735 us; speedup vs baseline: 5.2953x; 2.6828x over previous
//
#include <hip/hip_runtime.h>
#include <hip/hip_cooperative_groups.h>
#include <cmath>

namespace cg = cooperative_groups;

#define BB   64      // batch
#define DD   512     // data dim
#define UU   768     // units
#define GG   2304    // 3*UU
#define TIN  64
#define TOUT 64

// LDS layout (float4 units): 9 rows per matrix, row = [cc*3+gate]
#define OFF_WX0 0          // 9 rows x 128 f4
#define OFF_WH0 1152       // 9 x 192
#define OFF_WX1 2880       // 9 x 192
#define OFF_WH1 4608       // 9 x 192
#define OFF_WX2 6336       // 9 x 192
#define OFF_WH2 8064       // 9 x 192
#define LDS_F4  9792
#define LDS_BYTES (LDS_F4 * 16)   // 156,672 B <= 160 KiB

struct P {
  const float* inputs;
  const float* Wx[3];
  const float* Wh[3];
  const float* bi[3];
  const float* br[3];
  const float* h0[3];
  const float* Wd;
  const float* bd;
  const float* mean;
  const float* stdv;
  const float* WxT[3];
  const float* WhT[3];
  const float* WdT;
  float* out;
  float* ws;
};

__device__ __forceinline__ float sigm(float a) { return 1.0f / (1.0f + expf(-a)); }

__device__ __forceinline__ float dot4(float4 a, float4 b, float acc) {
  acc = fmaf(a.x, b.x, acc);
  acc = fmaf(a.y, b.y, acc);
  acc = fmaf(a.z, b.z, acc);
  acc = fmaf(a.w, b.w, acc);
  return acc;
}

// ---------------- tiled transpose: dst[c][r] = src[r][c] ----------------
__global__ __launch_bounds__(256) void transpose_kernel(
    const float* __restrict__ src, float* __restrict__ dst, int R, int C) {
  __shared__ float tile[32][33];
  const int bx = blockIdx.x * 32;
  const int by = blockIdx.y * 32;
  const int tx = threadIdx.x;
  const int ty = threadIdx.y;
  #pragma unroll
  for (int i = 0; i < 32; i += 8)
    tile[ty + i][tx] = src[(size_t)(by + ty + i) * C + (bx + tx)];
  __syncthreads();
  #pragma unroll
  for (int i = 0; i < 32; i += 8)
    dst[(size_t)(bx + ty + i) * R + (by + tx)] = tile[tx][ty + i];
}

// ---------------- GRU cell with LDS-resident weights ----------------
// block owns units c0..c0+2; threads: b = tid>>3, kq = tid&7.
// Lane kq handles float4 indices {t*8+kq} -> wave reads 128B contiguous LDS.
template<int NX4T, int KX4>
__device__ __forceinline__ void gru_cell_lds(
    const float* __restrict__ x, int xstride,
    const float4* __restrict__ wx, const float4* __restrict__ wh,
    const float* __restrict__ bi, const float* __restrict__ br,
    const float* __restrict__ hp, float* __restrict__ hn,
    int c0, int b, int kq)
{
  float ax[9], ah[9];
  #pragma unroll
  for (int r = 0; r < 9; ++r) { ax[r] = 0.f; ah[r] = 0.f; }

  const float4* xv = (const float4*)(x + (size_t)b * xstride);
  #pragma unroll 2
  for (int t = 0; t < NX4T; ++t) {
    const int idx = t * 8 + kq;
    float4 v = xv[idx];
    #pragma unroll
    for (int r = 0; r < 9; ++r) ax[r] = dot4(v, wx[r * KX4 + idx], ax[r]);
  }
  const float4* hv = (const float4*)(hp + (size_t)b * UU);
  #pragma unroll 2
  for (int t = 0; t < 24; ++t) {
    const int idx = t * 8 + kq;
    float4 v = hv[idx];
    #pragma unroll
    for (int r = 0; r < 9; ++r) ah[r] = dot4(v, wh[r * 192 + idx], ah[r]);
  }
  #pragma unroll
  for (int r = 0; r < 9; ++r) {
    ax[r] += __shfl_xor(ax[r], 1, 8); ax[r] += __shfl_xor(ax[r], 2, 8); ax[r] += __shfl_xor(ax[r], 4, 8);
    ah[r] += __shfl_xor(ah[r], 1, 8); ah[r] += __shfl_xor(ah[r], 2, 8); ah[r] += __shfl_xor(ah[r], 4, 8);
  }
  #pragma unroll
  for (int cc = 0; cc < 3; ++cc) {
    const int c = c0 + cc;
    float z  = sigm(ax[cc*3+0] + bi[c]        + ah[cc*3+0] + br[c]);
    float rr = sigm(ax[cc*3+1] + bi[c+UU]     + ah[cc*3+1] + br[c+UU]);
    float hc = tanhf(ax[cc*3+2] + bi[c+2*UU]  + rr * (ah[cc*3+2] + br[c+2*UU]));
    float hprev = hp[(size_t)b * UU + c];
    float hnv = z * hprev + (1.f - z) * hc;
    if (kq == 0) hn[(size_t)b * UU + c] = hnv;
  }
}

// ---------------- dense readout (WdT from global/L2) ----------------
__device__ __forceinline__ void dense_t(
    const float* __restrict__ h2, const float* __restrict__ WdT,
    const float* __restrict__ bd, const float* __restrict__ mean,
    const float* __restrict__ stdv, float* __restrict__ out,
    float* __restrict__ xbuf, int s, int blk, int tid)
{
  const int o  = blk * 128 + (tid >> 2);
  const int bb = o >> 9;
  const int dc = o & 511;
  const int kq = tid & 3;
  const float4* hv = (const float4*)(h2 + (size_t)bb * UU) + kq * 48;
  const float4* w  = (const float4*)(WdT + (size_t)dc * UU) + kq * 48;
  float acc = 0.f;
  #pragma unroll 4
  for (int i = 0; i < 48; ++i) acc = dot4(hv[i], w[i], acc);
  acc += __shfl_xor(acc, 1, 4);
  acc += __shfl_xor(acc, 2, 4);
  if (kq == 0) {
    float val = acc + bd[dc];
    out[((size_t)bb * TOUT + s) * DD + dc] = val;
    xbuf[(size_t)bb * DD + dc] = (val - mean[dc]) / stdv[dc];
  }
}

__global__ __launch_bounds__(512, 2) void gru_ar_kernel_lds(P p) {
  cg::grid_group grid = cg::this_grid();
  extern __shared__ float4 lds4[];
  const int tid = threadIdx.x;
  const int blk = blockIdx.x;
  const int b   = tid >> 3;
  const int kq  = tid & 7;
  const int c0  = blk * 3;

  float* hbuf = p.ws;                       // [2][3][BB][UU] ping-pong
  float* xbuf = p.ws + 2 * 3 * BB * UU;     // [BB][DD]

  // ---- stage this block's weight rows into LDS (coalesced, one-time) ----
  {
    const float* srcs[6] = { p.WxT[0], p.WhT[0], p.WxT[1], p.WhT[1], p.WxT[2], p.WhT[2] };
    const int    Ks[6]   = { DD, UU, UU, UU, UU, UU };
    const int    offs[6] = { OFF_WX0, OFF_WH0, OFF_WX1, OFF_WH1, OFF_WX2, OFF_WH2 };
    for (int m = 0; m < 6; ++m) {
      const int K4 = Ks[m] >> 2;
      for (int r = 0; r < 9; ++r) {
        const int cc = r / 3, g = r % 3;
        const float4* src = (const float4*)(srcs[m] + (size_t)(g * UU + c0 + cc) * Ks[m]);
        float4* dst = lds4 + offs[m] + (size_t)r * K4;
        for (int i = tid; i < K4; i += 512) dst[i] = src[i];
      }
    }
  }

  // init parity-0 h states
  {
    const int n = 3 * BB * UU;
    const int gsz = gridDim.x * blockDim.x;
    for (int i = blk * blockDim.x + tid; i < n; i += gsz) {
      int j = i / (BB * UU);
      int u = i % UU;
      hbuf[i] = p.h0[j][u];
    }
  }
  grid.sync();

  const float4* wx0 = lds4 + OFF_WX0;
  const float4* wh0 = lds4 + OFF_WH0;
  const float4* wx1 = lds4 + OFF_WX1;
  const float4* wh1 = lds4 + OFF_WH1;
  const float4* wx2 = lds4 + OFF_WX2;
  const float4* wh2 = lds4 + OFF_WH2;

  for (int t = 0; t < TIN + TOUT - 1; ++t) {
    const int pr = t & 1;
    const int pw = pr ^ 1;
    #pragma unroll 1
    for (int j = 0; j < 3; ++j) {
      const float* x; int xstride;
      if (j == 0) {
        if (t < TIN) { x = p.inputs + (size_t)t * DD; xstride = TIN * DD; }
        else         { x = xbuf;                       xstride = DD; }
      } else {
        x = hbuf + ((size_t)pw * 3 + (j - 1)) * BB * UU; xstride = UU;
      }
      const float* hp = hbuf + ((size_t)pr * 3 + j) * BB * UU;
      float*       hn = hbuf + ((size_t)pw * 3 + j) * BB * UU;
      if (j == 0)
        gru_cell_lds<16, 128>(x, xstride, wx0, wh0, p.bi[0], p.br[0], hp, hn, c0, b, kq);
      else if (j == 1)
        gru_cell_lds<24, 192>(x, xstride, wx1, wh1, p.bi[1], p.br[1], hp, hn, c0, b, kq);
      else
        gru_cell_lds<24, 192>(x, xstride, wx2, wh2, p.bi[2], p.br[2], hp, hn, c0, b, kq);
      grid.sync();
    }
    if (t >= TIN - 1) {
      const int s = t - (TIN - 1);
      const float* h2 = hbuf + ((size_t)pw * 3 + 2) * BB * UU;
      dense_t(h2, p.WdT, p.bd, p.mean, p.stdv, p.out, xbuf, s, blk, tid);
      grid.sync();
    }
  }
}

// ---------------- fallback: R2 kernel (global transposed weights) ----------------
__device__ __forceinline__ void gru_cell_t(
    const float* __restrict__ x, int xstride, int Kx,
    const float* __restrict__ WxT, const float* __restrict__ WhT,
    const float* __restrict__ bi, const float* __restrict__ br,
    const float* __restrict__ hp, float* __restrict__ hn,
    int blk, int b, int kq)
{
  const float* xrow = x + (size_t)b * xstride;
  const float* hrow = hp + (size_t)b * UU;
  const int nx4 = Kx >> 5;
  const int nh4 = UU >> 5;
  const float4* xv = (const float4*)xrow + kq * nx4;
  const float4* hv = (const float4*)hrow + kq * nh4;
  #pragma unroll 1
  for (int cc = 0; cc < 3; ++cc) {
    const int c = blk * 3 + cc;
    float axz = 0.f, axr = 0.f, axh = 0.f, ahz = 0.f, ahr = 0.f, ahh = 0.f;
    {
      const float4* wz = (const float4*)(WxT + (size_t)c          * Kx) + kq * nx4;
      const float4* wr = (const float4*)(WxT + (size_t)(c +   UU) * Kx) + kq * nx4;
      const float4* wh = (const float4*)(WxT + (size_t)(c + 2*UU) * Kx) + kq * nx4;
      #pragma unroll 4
      for (int i = 0; i < nx4; ++i) {
        float4 v = xv[i];
        axz = dot4(v, wz[i], axz); axr = dot4(v, wr[i], axr); axh = dot4(v, wh[i], axh);
      }
    }
    {
      const float4* wz = (const float4*)(WhT + (size_t)c          * UU) + kq * nh4;
      const float4* wr = (const float4*)(WhT + (size_t)(c +   UU) * UU) + kq * nh4;
      const float4* wh = (const float4*)(WhT + (size_t)(c + 2*UU) * UU) + kq * nh4;
      #pragma unroll 4
      for (int i = 0; i < nh4; ++i) {
        float4 v = hv[i];
        ahz = dot4(v, wz[i], ahz); ahr = dot4(v, wr[i], ahr); ahh = dot4(v, wh[i], ahh);
      }
    }
    axz += __shfl_xor(axz,1,8); axz += __shfl_xor(axz,2,8); axz += __shfl_xor(axz,4,8);
    axr += __shfl_xor(axr,1,8); axr += __shfl_xor(axr,2,8); axr += __shfl_xor(axr,4,8);
    axh += __shfl_xor(axh,1,8); axh += __shfl_xor(axh,2,8); axh += __shfl_xor(axh,4,8);
    ahz += __shfl_xor(ahz,1,8); ahz += __shfl_xor(ahz,2,8); ahz += __shfl_xor(ahz,4,8);
    ahr += __shfl_xor(ahr,1,8); ahr += __shfl_xor(ahr,2,8); ahr += __shfl_xor(ahr,4,8);
    ahh += __shfl_xor(ahh,1,8); ahh += __shfl_xor(ahh,2,8); ahh += __shfl_xor(ahh,4,8);
    float z  = sigm(axz + bi[c]         + ahz + br[c]);
    float r  = sigm(axr + bi[c + UU]    + ahr + br[c + UU]);
    float hc = tanhf(axh + bi[c + 2*UU] + r * (ahh + br[c + 2*UU]));
    float hnv = z * hrow[c] + (1.f - z) * hc;
    if (kq == 0) hn[(size_t)b * UU + c] = hnv;
  }
}

__global__ __launch_bounds__(512, 2) void gru_ar_kernel_glb(P p) {
  cg::grid_group grid = cg::this_grid();
  const int tid = threadIdx.x;
  const int blk = blockIdx.x;
  const int b   = tid >> 3;
  const int kq  = tid & 7;
  float* hbuf = p.ws;
  float* xbuf = p.ws + 2 * 3 * BB * UU;
  {
    const int n = 3 * BB * UU;
    const int gsz = gridDim.x * blockDim.x;
    for (int i = blk * blockDim.x + tid; i < n; i += gsz) {
      int j = i / (BB * UU);
      int u = i % UU;
      hbuf[i] = p.h0[j][u];
    }
  }
  grid.sync();
  for (int t = 0; t < TIN + TOUT - 1; ++t) {
    const int pr = t & 1;
    const int pw = pr ^ 1;
    for (int j = 0; j < 3; ++j) {
      const float* x; int xstride, Kx;
      if (j == 0) {
        if (t < TIN) { x = p.inputs + (size_t)t * DD; xstride = TIN * DD; }
        else         { x = xbuf;                       xstride = DD; }
        Kx = DD;
      } else {
        x = hbuf + ((size_t)pw * 3 + (j - 1)) * BB * UU; xstride = UU; Kx = UU;
      }
      const float* hp = hbuf + ((size_t)pr * 3 + j) * BB * UU;
      float*       hn = hbuf + ((size_t)pw * 3 + j) * BB * UU;
      gru_cell_t(x, xstride, Kx, p.WxT[j], p.WhT[j], p.bi[j], p.br[j], hp, hn, blk, b, kq);
      grid.sync();
    }
    if (t >= TIN - 1) {
      const int s = t - (TIN - 1);
      const float* h2 = hbuf + ((size_t)pw * 3 + 2) * BB * UU;
      dense_t(h2, p.WdT, p.bd, p.mean, p.stdv, p.out, xbuf, s, blk, tid);
      grid.sync();
    }
  }
}

extern "C" void kernel_launch(void* const* d_in, const int* in_sizes, int n_in,
                              void* d_out, int out_size, void* d_ws, size_t ws_size,
                              hipStream_t stream) {
  P p;
  p.inputs = (const float*)d_in[0];
  int k = 1;
  for (int j = 0; j < 3; ++j) {
    p.Wx[j] = (const float*)d_in[k++];
    p.Wh[j] = (const float*)d_in[k++];
    p.bi[j] = (const float*)d_in[k++];
    p.br[j] = (const float*)d_in[k++];
    p.h0[j] = (const float*)d_in[k++];
  }
  p.Wd   = (const float*)d_in[k++];
  p.bd   = (const float*)d_in[k++];
  p.mean = (const float*)d_in[k++];
  p.stdv = (const float*)d_in[k++];
  p.out  = (float*)d_out;
  p.ws   = (float*)d_ws;

  // ws layout: hbuf | xbuf | WxT/WhT x3 | WdT
  size_t off = 2 * 3 * BB * UU + BB * DD;
  float* wsf = (float*)d_ws;
  const int KxDims[3] = { DD, UU, UU };
  float* WxT[3]; float* WhT[3]; float* WdT;
  for (int j = 0; j < 3; ++j) {
    WxT[j] = wsf + off; off += (size_t)GG * KxDims[j];
    WhT[j] = wsf + off; off += (size_t)GG * UU;
  }
  WdT = wsf + off; off += (size_t)DD * UU;

  dim3 tb(32, 8);
  for (int j = 0; j < 3; ++j) {
    transpose_kernel<<<dim3(GG / 32, KxDims[j] / 32), tb, 0, stream>>>(
        p.Wx[j], WxT[j], KxDims[j], GG);
    transpose_kernel<<<dim3(GG / 32, UU / 32), tb, 0, stream>>>(
        p.Wh[j], WhT[j], UU, GG);
  }
  transpose_kernel<<<dim3(DD / 32, UU / 32), tb, 0, stream>>>(p.Wd, WdT, UU, DD);
  for (int j = 0; j < 3; ++j) { p.WxT[j] = WxT[j]; p.WhT[j] = WhT[j]; }
  p.WdT = WdT;

  void* args[] = { &p };
  hipError_t e = hipFuncSetAttribute(
      reinterpret_cast<const void*>(gru_ar_kernel_lds),
      hipFuncAttributeMaxDynamicSharedMemorySize, LDS_BYTES);
  if (e == hipSuccess) {
    e = hipLaunchCooperativeKernel((void*)gru_ar_kernel_lds, dim3(256), dim3(512),
                                   args, LDS_BYTES, stream);
  }
  if (e != hipSuccess) {
    hipLaunchCooperativeKernel((void*)gru_ar_kernel_glb, dim3(256), dim3(512),
                               args, 0, stream);
  }
}